// Round 17
// baseline (412.813 us; speedup 1.0000x reference)
//
#include <hip/hip_runtime.h>

// ---------------------------------------------------------------------------
// LightGCN on MI355X, v6 (resubmit — R16 bench never ran, GPU timeout):
//   v5b + pair-gather SpMM (R15: VALUBusy 70%, BW fell 4.0->3.33 TB/s — spmm
//   became VALU-co-bound on 2B scalar bf16 gathers). 32 lanes/row, uint loads
//   = 2 edges/iter, halved VALU/byte. initz fused into bsort_k.
// ---------------------------------------------------------------------------

#define MAXBUK 640   // >= ceil(150016/256) = 587
#define CHUNK 4096   // edges per partition block
#define MAXBE 12288  // max edges per 256-node bucket (avg item bucket ~10.2k)

__device__ __forceinline__ ushort f2bf(float f) {  // round-to-nearest-even
  union { float f; unsigned int i; } cv;
  cv.f = f;
  unsigned int u = cv.i + 0x7FFFu + ((cv.i >> 16) & 1u);
  return (ushort)(u >> 16);
}

__device__ __forceinline__ float bflo(unsigned int w) {  // low bf16 of packed pair
  union { unsigned int i; float f; } cv;
  cv.i = w << 16;
  return cv.f;
}

__device__ __forceinline__ float bfhi(unsigned int w) {  // high bf16 of packed pair
  union { unsigned int i; float f; } cv;
  cv.i = w & 0xFFFF0000u;
  return cv.f;
}

__device__ __forceinline__ int wave_incl_scan(int v) {
  int lane = threadIdx.x & 63;
#pragma unroll
  for (int off = 1; off < 64; off <<= 1) {
    int t = __shfl_up(v, off, 64);
    if (lane >= off) v += t;
  }
  return v;
}

// --- bucket histogram: LDS-aggregated ---------------------------------------

__global__ __launch_bounds__(256) void bhist_k(const int4* __restrict__ col4, int E4,
                                               const int* __restrict__ col, int E,
                                               int* __restrict__ bcnt, int nbuk) {
  __shared__ int lc[MAXBUK];
  for (int b = threadIdx.x; b < nbuk; b += 256) lc[b] = 0;
  __syncthreads();
  int i = blockIdx.x * 256 + threadIdx.x;
  int stride = gridDim.x * 256;
  for (int j = i; j < E4; j += stride) {
    int4 c = col4[j];
    atomicAdd(&lc[c.x >> 8], 1);
    atomicAdd(&lc[c.y >> 8], 1);
    atomicAdd(&lc[c.z >> 8], 1);
    atomicAdd(&lc[c.w >> 8], 1);
  }
  for (int j = E4 * 4 + i; j < E; j += stride) atomicAdd(&lc[col[j] >> 8], 1);
  __syncthreads();
  for (int b = threadIdx.x; b < nbuk; b += 256) {
    int c = lc[b];
    if (c) atomicAdd(&bcnt[b], c);
  }
}

// --- single-block scan -> boffs + gcursor; also zeroes dummy z rows ---------

__global__ void bscan_k(const int* __restrict__ bcnt, int* __restrict__ boffs,
                        int* __restrict__ gcursor, ushort* __restrict__ za,
                        ushort* __restrict__ zb, int nbuk, int E, int N) {
  int tid = threadIdx.x;  // 1024 >= nbuk
  int v = (tid < nbuk) ? bcnt[tid] : 0;
  int incl = wave_incl_scan(v);
  __shared__ int wsum[16];
  int wid = tid >> 6, lane = tid & 63;
  if (lane == 63) wsum[wid] = incl;
  __syncthreads();
  if (tid == 0) {
    int run = 0;
#pragma unroll
    for (int j = 0; j < 16; ++j) { int t = wsum[j]; wsum[j] = run; run += t; }
  }
  __syncthreads();
  int excl = incl - v + wsum[wid];
  if (tid < nbuk) {
    boffs[tid] = excl;
    gcursor[tid] = excl;
  }
  if (tid == 0) boffs[nbuk] = E;
  if (tid < 64) {  // zero dummy row N in both z buffers
    za[N * 64 + tid] = 0;
    zb[N * 64 + tid] = 0;
  }
}

// --- pass A: bucket partition, record = src | dst_rel<<18 (4B), coalesced ---

__global__ __launch_bounds__(256) void part_k(
    const int* __restrict__ row, const int* __restrict__ col, int E,
    int* __restrict__ gcursor, int* __restrict__ ebk, int nbuk) {
  __shared__ int cnt[MAXBUK];
  __shared__ int start[MAXBUK];
  __shared__ int ghead[MAXBUK];
  __shared__ int ebuf[CHUNK];
  __shared__ int gofs[CHUNK];
  __shared__ int wsum[4];

  const int tid = threadIdx.x;
  const int base = blockIdx.x * CHUNK;
  const int m = min(CHUNK, E - base);

  for (int b = tid; b < nbuk; b += 256) cnt[b] = 0;
  __syncthreads();

  int rec[16];
  int bb[16];
#pragma unroll
  for (int k = 0; k < 16; ++k) {
    int idx = k * 256 + tid;
    bb[k] = -1;
    if (idx < m) {
      int i = base + idx;
      int c = col[i];
      int r = row[i];
      rec[k] = r | ((c & 255) << 18);
      bb[k] = c >> 8;
      atomicAdd(&cnt[c >> 8], 1);
    }
  }
  __syncthreads();

  // exclusive scan of cnt[0..nbuk) into start[]
  const int b0 = tid * 3;  // 3 buckets/thread covers 768 >= nbuk
  int lc0 = (b0 + 0 < nbuk) ? cnt[b0 + 0] : 0;
  int lc1 = (b0 + 1 < nbuk) ? cnt[b0 + 1] : 0;
  int lc2 = (b0 + 2 < nbuk) ? cnt[b0 + 2] : 0;
  int s = lc0 + lc1 + lc2;
  int incl = wave_incl_scan(s);
  int wid = tid >> 6, lane = tid & 63;
  if (lane == 63) wsum[wid] = incl;
  __syncthreads();
  int wb = 0;
#pragma unroll
  for (int j = 0; j < 4; ++j)
    if (j < wid) wb += wsum[j];
  int run = incl - s + wb;
  if (b0 + 0 < nbuk) { start[b0 + 0] = run; run += lc0; }
  if (b0 + 1 < nbuk) { start[b0 + 1] = run; run += lc1; }
  if (b0 + 2 < nbuk) { start[b0 + 2] = run; run += lc2; }
  __syncthreads();

  // reserve global runs
  for (int b = tid; b < nbuk; b += 256) {
    int cb = cnt[b];
    if (cb > 0) {
      int g = atomicAdd(&gcursor[b], cb);
      ghead[b] = g - start[b];
    }
  }
  __syncthreads();

  // place into ordered LDS buffer (start[] doubles as running cursor)
#pragma unroll
  for (int k = 0; k < 16; ++k) {
    if (bb[k] >= 0) {
      int slot = atomicAdd(&start[bb[k]], 1);
      ebuf[slot] = rec[k];
      gofs[slot] = ghead[bb[k]];
    }
  }
  __syncthreads();

  for (int s2 = tid; s2 < m; s2 += 256) ebk[gofs[s2] + s2] = ebuf[s2];
}

// --- pass B: counting sort -> srcs; emits offs/dis/dis2 + fused z0 init -----

__global__ __launch_bounds__(256) void bsort_k(
    const int* __restrict__ boffs, const int* __restrict__ ebk,
    int* __restrict__ srcs, int* __restrict__ offs,
    float* __restrict__ dis, float* __restrict__ dis2,
    const float4* __restrict__ uw4, const float4* __restrict__ iw4,
    ushort* __restrict__ za, int N, int NU, int E) {
  __shared__ int cnt[256];
  __shared__ float disv[256];
  __shared__ int wsum[4];
  __shared__ int obuf[MAXBE];
  const int tid = threadIdx.x;
  const int node0 = blockIdx.x << 8;
  const int nn = min(256, N - node0);
  const int g0 = boffs[blockIdx.x];
  const int g1 = boffs[blockIdx.x + 1];
  const int m = g1 - g0;

  cnt[tid] = 0;
  __syncthreads();
  for (int i = tid; i < m; i += 256) atomicAdd(&cnt[(ebk[g0 + i] >> 18) & 255], 1);
  __syncthreads();

  int v = cnt[tid];  // = degree of node0+tid (bucketing is exact by dst)
  int incl = wave_incl_scan(v);
  int wid = tid >> 6, lane = tid & 63;
  if (lane == 63) wsum[wid] = incl;
  __syncthreads();
  int wb = 0;
#pragma unroll
  for (int j = 0; j < 4; ++j)
    if (j < wid) wb += wsum[j];
  int excl = incl - v + wb;

  float dv = v > 0 ? 1.0f / sqrtf((float)v) : 0.0f;
  disv[tid] = dv;
  if (tid < nn) {
    int node = node0 + tid;
    offs[node] = g0 + excl;
    dis[node] = dv;
    dis2[node] = dv * dv;
  }
  if (blockIdx.x == 0 && tid == 0) offs[N] = E;

  __syncthreads();
  cnt[tid] = excl;
  __syncthreads();

  for (int i = tid; i < m; i += 256) {
    int r = ebk[g0 + i];
    int slot = atomicAdd(&cnt[(r >> 18) & 255], 1);
    if (slot < MAXBE) obuf[slot] = r & 0x3FFFF;
  }
  __syncthreads();
  for (int i = tid; i < m; i += 256) srcs[g0 + i] = obuf[i];

  // fused z0 init for this block's nodes: za = bf16(dis .* x0)
  for (int g = tid; g < nn * 16; g += 256) {
    int rel = g >> 4;
    int comp = g & 15;
    int node = node0 + rel;
    float4 x = (node < NU) ? uw4[node * 16 + comp] : iw4[(node - NU) * 16 + comp];
    float d = disv[rel];
    ushort4 o;
    o.x = f2bf(x.x * d);
    o.y = f2bf(x.y * d);
    o.z = f2bf(x.z * d);
    o.w = f2bf(x.w * d);
    *reinterpret_cast<ushort4*>(&za[node * 64 + comp * 4]) = o;
  }
}

// --- SpMM: wave-per-node, pair-gather (32 lanes/row, uint = 2 bf16 dims) ----

template <int LAYER>
__global__ __launch_bounds__(256) void spmm_k(
    const int* __restrict__ offs, const int* __restrict__ srcs,
    const ushort* __restrict__ zin, ushort* __restrict__ zout,
    const float* __restrict__ uw, const float* __restrict__ iw,
    const float* __restrict__ dis, const float* __restrict__ dis2,
    float* __restrict__ dout, int N, int NU) {
  int wid = blockIdx.x * 4 + (threadIdx.x >> 6);
  int lane = threadIdx.x & 63;
  if (wid >= N) return;
  int NI = N - NU;
  int n = (wid < NI) ? (NU + wid) : (wid - NI);  // items (2x degree) first
  n = __builtin_amdgcn_readfirstlane(n);
  int e0 = __builtin_amdgcn_readfirstlane(offs[n]);
  int e1 = __builtin_amdgcn_readfirstlane(offs[n + 1]);

  const int li = lane & 31;   // dim pair index: dims 2li, 2li+1
  const int hi = lane >> 5;   // 0 -> edge A, 1 -> edge B

  float ax = 0.0f, ay = 0.0f;
  for (int base = e0; base < e1; base += 64) {
    int rem = e1 - base;
    int src = (lane < rem) ? srcs[base + lane] : N;  // lanes past end -> zero row
    int kk = min(rem, 64);
    for (int j = 0; j < kk; j += 8) {
#pragma unroll
      for (int t = 0; t < 4; ++t) {
        int sA = __builtin_amdgcn_readlane(src, j + 2 * t);
        int sB = __builtin_amdgcn_readlane(src, j + 2 * t + 1);
        int s = hi ? sB : sA;
        unsigned int w32 =
            *reinterpret_cast<const unsigned int*>(&zin[(s << 6) + li * 2]);
        ax += bflo(w32);
        ay += bfhi(w32);
      }
    }
  }
  // merge the two edge-halves (lane l and l+32 hold the same dims)
  ax += __shfl_xor(ax, 32, 64);
  ay += __shfl_xor(ay, 32, 64);

  if (hi == 0) {
    float d1 = dis[n];
    int o = n * 64 + li * 2;
    float xlx = d1 * ax, xly = d1 * ay;
    if (LAYER == 1) {
      const float* xp = (n < NU) ? (uw + o) : (iw + (o - NU * 64));
      float2 x0 = *reinterpret_cast<const float2*>(xp);
      float z2 = dis2[n];
      *reinterpret_cast<ushort2*>(&zout[o]) = make_ushort2(f2bf(z2 * ax), f2bf(z2 * ay));
      *reinterpret_cast<float2*>(&dout[o]) = make_float2(x0.x + xlx, x0.y + xly);
    } else if (LAYER == 2) {
      float z2 = dis2[n];
      *reinterpret_cast<ushort2*>(&zout[o]) = make_ushort2(f2bf(z2 * ax), f2bf(z2 * ay));
      float2 dc = *reinterpret_cast<const float2*>(&dout[o]);
      *reinterpret_cast<float2*>(&dout[o]) = make_float2(dc.x + xlx, dc.y + xly);
    } else {
      float2 dc = *reinterpret_cast<const float2*>(&dout[o]);
      *reinterpret_cast<float2*>(&dout[o]) =
          make_float2((dc.x + xlx) * 0.25f, (dc.y + xly) * 0.25f);
    }
  }
}

extern "C" void kernel_launch(void* const* d_in, const int* in_sizes, int n_in,
                              void* d_out, int out_size, void* d_ws, size_t ws_size,
                              hipStream_t stream) {
  const int* edge_index = (const int*)d_in[0];
  const float* uw = (const float*)d_in[1];
  const float* iw = (const float*)d_in[2];
  const int E = in_sizes[0] / 2;
  const int NU = in_sizes[1] / 64;
  const int NI = in_sizes[2] / 64;
  const int N = NU + NI;
  const int nbuk = (N + 255) >> 8;

  const int* row = edge_index;      // edge_index[0, :]
  const int* col = edge_index + E;  // edge_index[1, :]

  char* w = (char*)d_ws;
  auto carve = [&](size_t bytes) {
    char* p = w;
    w += (bytes + 255) & ~(size_t)255;
    return (void*)p;
  };
  int* bcnt = (int*)carve((size_t)MAXBUK * sizeof(int));
  int* boffs = (int*)carve((size_t)(MAXBUK + 1) * sizeof(int));
  int* gcursor = (int*)carve((size_t)MAXBUK * sizeof(int));
  int* offs = (int*)carve((size_t)(N + 1) * sizeof(int));
  float* dis = (float*)carve((size_t)N * sizeof(float));
  float* dis2 = (float*)carve((size_t)N * sizeof(float));
  int* ebk = (int*)carve((size_t)E * sizeof(int));
  int* srcs = (int*)carve((size_t)E * sizeof(int));
  ushort* za = (ushort*)carve((size_t)(N + 1) * 64 * sizeof(ushort));
  ushort* zb = (ushort*)carve((size_t)(N + 1) * 64 * sizeof(ushort));

  float* out = (float*)d_out;

  (void)hipMemsetAsync(bcnt, 0, (size_t)MAXBUK * sizeof(int), stream);
  bhist_k<<<512, 256, 0, stream>>>((const int4*)col, E / 4, col, E, bcnt, nbuk);
  bscan_k<<<1, 1024, 0, stream>>>(bcnt, boffs, gcursor, za, zb, nbuk, E, N);
  part_k<<<(E + CHUNK - 1) / CHUNK, 256, 0, stream>>>(row, col, E, gcursor, ebk, nbuk);
  bsort_k<<<nbuk, 256, 0, stream>>>(boffs, ebk, srcs, offs, dis, dis2,
                                    (const float4*)uw, (const float4*)iw, za, N, NU, E);

  int sb = (N + 3) / 4;  // 4 waves (nodes) per 256-thread block
  spmm_k<1><<<sb, 256, 0, stream>>>(offs, srcs, za, zb, uw, iw, dis, dis2, out, N, NU);
  spmm_k<2><<<sb, 256, 0, stream>>>(offs, srcs, zb, za, uw, iw, dis, dis2, out, N, NU);
  spmm_k<3><<<sb, 256, 0, stream>>>(offs, srcs, za, zb, uw, iw, dis, dis2, out, N, NU);
}